// Round 1
// 1493.773 us; speedup vs baseline: 1.0697x; 1.0697x over previous
//
#include <hip/hip_runtime.h>
#include <stdint.h>

#define DD 256
#define LL 4
#define HH 8

#define BM 128
#define BN 128
#define BK 32
#define LDA 40      // LDS row stride in bf16 elems (80 B, 16B-aligned, 2-way bank alias = free)
#define KSTR 136    // K-tile LDS stride (ushort): 272B -> rows spread 4 banks apart
#define QSTR 264    // q-tile LDS stride (ushort): 528B -> rows spread 4 banks apart

typedef __bf16 bf16_t;
typedef bf16_t bf16x8 __attribute__((ext_vector_type(8)));
typedef float f32x4 __attribute__((ext_vector_type(4)));

__device__ __forceinline__ ushort f2bf(float f) {
  union { float f; uint32_t u; } v; v.f = f;
  uint32_t r = v.u + 0x7FFFu + ((v.u >> 16) & 1u);
  return (ushort)(r >> 16);
}
__device__ __forceinline__ float bf2f(ushort u) {
  union { uint32_t u; float f; } v; v.u = ((uint32_t)u) << 16;
  return v.f;
}
// mask format: 0 = int32, 1 = uint8 (raw bool), 2 = float32
__device__ __forceinline__ bool mval(const void* m, int fmt, size_t idx) {
  if (fmt == 1) return ((const uint8_t*)m)[idx] != 0;
  if (fmt == 2) return ((const float*)m)[idx] != 0.0f;
  return ((const int*)m)[idx] != 0;
}

__global__ void detect_mask_k(const uint8_t* m, int* flag) {
  if (threadIdx.x == 0 && blockIdx.x == 0) {
    bool anybig = false, anyoff = false;
    for (int i = 0; i < 256; i++) {
      uint8_t v = m[i];
      if (v > 1) anybig = true;
      if ((i & 3) && v) anyoff = true;
    }
    *flag = anybig ? 2 : (anyoff ? 1 : 0);
  }
}

__global__ void cast_w_k(const float* __restrict__ ipw, const float* __restrict__ opw,
                         const float* __restrict__ f1w, const float* __restrict__ f2w,
                         const float* __restrict__ svw, ushort* __restrict__ W) {
  int i = blockIdx.x * 256 + threadIdx.x;
  if (i >= 458752) return;
  float v;
  if (i < 196608) v = ipw[i];
  else if (i < 262144) v = opw[i - 196608];
  else if (i < 327680) v = f1w[i - 262144];
  else if (i < 393216) v = f2w[i - 327680];
  else v = svw[i - 393216];
  W[i] = f2bf(v);
}

// EPI: 0 = plain bf16 out (+bias, opt relu), 3 = save->bank slot3 (saved rows only)
template<int ABF16, int EPI>
__global__ __launch_bounds__(256, 2)
void gemm_k(const void* __restrict__ Aptr, const ushort* __restrict__ Bw,
            const float* __restrict__ bias, void* __restrict__ Cout, int M,
            const float* __restrict__ scores, float* __restrict__ bank_out,
            int relu_flag) {
  __shared__ ushort Asm[BM * LDA];
  __shared__ ushort Bsm[BN * LDA];

  // nt fastest-varying: the two blocks sharing an A tile are dispatch-adjacent
  // -> second read hits L2/L3 instead of HBM.
  const int nt = blockIdx.x, mt = blockIdx.y;
  const int tid = threadIdx.x;
  const int wave = tid >> 6, lane = tid & 63;
  const int wm = wave >> 1, wn = wave & 1;
  const int llo = lane & 15, lhi = lane >> 4;
  const int row0 = mt * BM;

  f32x4 acc[4][4];
#pragma unroll
  for (int i = 0; i < 4; i++)
#pragma unroll
    for (int j = 0; j < 4; j++) {
      f32x4 z = {0.0f, 0.0f, 0.0f, 0.0f};
      acc[i][j] = z;
    }

  const int ar = tid >> 1;
  const int acb = (tid & 1) * 16;

  for (int k0 = 0; k0 < DD; k0 += BK) {
    // ---- stage A tile [128 x 32] (convert fp32->bf16 if needed) ----
    {
      ushort tmp[16];
      int gr = row0 + ar;
      if (ABF16) {
        if (gr < M) {
          const uint4* p = (const uint4*)((const ushort*)Aptr + (size_t)gr * DD + k0 + acb);
          *(uint4*)(tmp) = p[0];
          *(uint4*)(tmp + 8) = p[1];
        } else {
#pragma unroll
          for (int i = 0; i < 16; i++) tmp[i] = 0;
        }
      } else {
        if (gr < M) {
          const float4* p = (const float4*)((const float*)Aptr + (size_t)gr * DD + k0 + acb);
          float4 f0 = p[0], f1 = p[1], f2 = p[2], f3 = p[3];
          tmp[0] = f2bf(f0.x); tmp[1] = f2bf(f0.y); tmp[2] = f2bf(f0.z); tmp[3] = f2bf(f0.w);
          tmp[4] = f2bf(f1.x); tmp[5] = f2bf(f1.y); tmp[6] = f2bf(f1.z); tmp[7] = f2bf(f1.w);
          tmp[8] = f2bf(f2.x); tmp[9] = f2bf(f2.y); tmp[10] = f2bf(f2.z); tmp[11] = f2bf(f2.w);
          tmp[12] = f2bf(f3.x); tmp[13] = f2bf(f3.y); tmp[14] = f2bf(f3.z); tmp[15] = f2bf(f3.w);
        } else {
#pragma unroll
          for (int i = 0; i < 16; i++) tmp[i] = 0;
        }
      }
      ushort* dst = Asm + ar * LDA + acb;
      *(uint4*)dst = *(uint4*)tmp;
      *(uint4*)(dst + 8) = *(uint4*)(tmp + 8);
    }
    // ---- stage B tile [128 cols x 32 k] from bf16 weights (B^T layout = W row-major) ----
    if (tid < BN) {
      const ushort* src = Bw + (size_t)(nt * BN + tid) * DD + k0;
      ushort* dst = Bsm + tid * LDA;
      *(uint4*)(dst)      = *(const uint4*)(src);
      *(uint4*)(dst + 8)  = *(const uint4*)(src + 8);
      *(uint4*)(dst + 16) = *(const uint4*)(src + 16);
      *(uint4*)(dst + 24) = *(const uint4*)(src + 24);
    }
    __syncthreads();
    bf16x8 af[4], bfr[4];
#pragma unroll
    for (int i = 0; i < 4; i++)
      af[i] = *(const bf16x8*)(Asm + (wm * 64 + i * 16 + llo) * LDA + lhi * 8);
#pragma unroll
    for (int j = 0; j < 4; j++)
      bfr[j] = *(const bf16x8*)(Bsm + (wn * 64 + j * 16 + llo) * LDA + lhi * 8);
#pragma unroll
    for (int i = 0; i < 4; i++)
#pragma unroll
      for (int j = 0; j < 4; j++)
        acc[i][j] = __builtin_amdgcn_mfma_f32_16x16x32_bf16(af[i], bfr[j], acc[i][j], 0, 0, 0);
    __syncthreads();
  }

  // ---- epilogues ----
  if (EPI == 0) {
    ushort* C = (ushort*)Cout;
#pragma unroll
    for (int i = 0; i < 4; i++)
#pragma unroll
      for (int j = 0; j < 4; j++)
#pragma unroll
        for (int r = 0; r < 4; r++) {
          int rl = wm * 64 + i * 16 + lhi * 4 + r;
          int gr = row0 + rl;
          if (gr < M) {
            int gc = nt * BN + wn * 64 + j * 16 + llo;
            float v = acc[i][j][r] + bias[gc];
            if (relu_flag) v = fmaxf(v, 0.0f);
            C[(size_t)gr * DD + gc] = f2bf(v);
          }
        }
  } else {
#pragma unroll
    for (int i = 0; i < 4; i++)
#pragma unroll
      for (int j = 0; j < 4; j++)
#pragma unroll
        for (int r = 0; r < 4; r++) {
          int rl = wm * 64 + i * 16 + lhi * 4 + r;
          int gr = row0 + rl;
          if (gr < M && scores[gr] > 0.0f) {
            int gc = nt * BN + wn * 64 + j * 16 + llo;
            bank_out[(size_t)gr * 1024 + 768 + gc] = acc[i][j][r] + bias[gc];
          }
        }
  }
}

// ---------------------------------------------------------------------------
// Fused K/V projection + logits + softmax + ctx + bank shift/copy.
// One block = 128 mem_bank rows = exactly 32 whole tracks (L=4).
// 512 threads = 8 waves (2 wm x 4 wn); cols 0..255 = K proj, 256..511 = V proj
// (Wk and Wv rows are contiguous in the cast weight buffer).
// V stays in fp32 accumulators; ctx is an in-register 4-term reduction
// (the 4 l-rows of a track land in one lane's acc[i][j][0..3]).
// ---------------------------------------------------------------------------
__global__ __launch_bounds__(512, 2)
void kv_attn_k(const float* __restrict__ memb, const ushort* __restrict__ Wkv,
               const float* __restrict__ ipb, const ushort* __restrict__ qbuf,
               ushort* __restrict__ ctx_out, const void* __restrict__ mask,
               const int* __restrict__ flag, const float* __restrict__ scores,
               float* __restrict__ out_bank, float* __restrict__ out_mask, int N) {
  extern __shared__ char smem[];
  ushort* Asm = (ushort*)smem;                 // staging: 128 x LDA
  ushort* Bsm = Asm + 128 * LDA;               // staging: 512 x LDA
  ushort* Ksm = (ushort*)smem;                 // epilogue overlay: 128 x KSTR bf16
  ushort* qsm = Ksm + 128 * KSTR;              // 32 x QSTR bf16
  float* attn_s = (float*)(qsm + 32 * QSTR);   // [32 tracks][8 heads][4] fp32

  const int mt = blockIdx.x;
  const int tid = threadIdx.x;
  const int wave = tid >> 6, lane = tid & 63;
  const int wm = wave >> 2, wn = wave & 3;
  const int llo = lane & 15, lhi = lane >> 4;
  const int row0 = mt * 128;
  const int trk0 = mt * 32;
  const int M = N * 4;

  f32x4 acc[4][8];
#pragma unroll
  for (int i = 0; i < 4; i++)
#pragma unroll
    for (int j = 0; j < 8; j++) {
      f32x4 z = {0.0f, 0.0f, 0.0f, 0.0f};
      acc[i][j] = z;
    }

  const int ar = tid >> 2;            // 0..127
  const int acb = (tid & 3) * 8;      // 0,8,16,24

  for (int k0 = 0; k0 < DD; k0 += BK) {
    // ---- stage A tile [128 x 32] fp32 -> bf16 (8 elems / thread) ----
    {
      ushort tmp[8];
      int gr = row0 + ar;
      if (gr < M) {
        const float4* p = (const float4*)(memb + (size_t)gr * DD + k0 + acb);
        float4 f0 = p[0], f1 = p[1];
        tmp[0] = f2bf(f0.x); tmp[1] = f2bf(f0.y); tmp[2] = f2bf(f0.z); tmp[3] = f2bf(f0.w);
        tmp[4] = f2bf(f1.x); tmp[5] = f2bf(f1.y); tmp[6] = f2bf(f1.z); tmp[7] = f2bf(f1.w);
      } else {
#pragma unroll
        for (int i = 0; i < 8; i++) tmp[i] = 0;
      }
      *(uint4*)(Asm + ar * LDA + acb) = *(uint4*)tmp;
    }
    // ---- stage B tile [512 cols x 32 k]: one row per thread ----
    {
      const ushort* src = Wkv + (size_t)tid * DD + k0;
      ushort* dst = Bsm + tid * LDA;
      *(uint4*)(dst)      = *(const uint4*)(src);
      *(uint4*)(dst + 8)  = *(const uint4*)(src + 8);
      *(uint4*)(dst + 16) = *(const uint4*)(src + 16);
      *(uint4*)(dst + 24) = *(const uint4*)(src + 24);
    }
    __syncthreads();
    bf16x8 af[4], bfr[8];
#pragma unroll
    for (int i = 0; i < 4; i++)
      af[i] = *(const bf16x8*)(Asm + (wm * 64 + i * 16 + llo) * LDA + lhi * 8);
#pragma unroll
    for (int j = 0; j < 8; j++)
      bfr[j] = *(const bf16x8*)(Bsm + (wn * 128 + j * 16 + llo) * LDA + lhi * 8);
#pragma unroll
    for (int i = 0; i < 4; i++)
#pragma unroll
      for (int j = 0; j < 8; j++)
        acc[i][j] = __builtin_amdgcn_mfma_f32_16x16x32_bf16(af[i], bfr[j], acc[i][j], 0, 0, 0);
    __syncthreads();
  }

  const int fmt = *flag;

  // ---- phase 1: K waves (wn<2, acc dead after this) dump K+bias to LDS;
  //               V waves (wn>=2, acc must survive) stage q tile (low-reg work) ----
  if (wn < 2) {
#pragma unroll
    for (int j = 0; j < 8; j++) {
      int cl = wn * 128 + j * 16 + llo;
      float kb = ipb[256 + cl];
#pragma unroll
      for (int i = 0; i < 4; i++)
#pragma unroll
        for (int r = 0; r < 4; r++) {
          int rl = wm * 64 + i * 16 + lhi * 4 + r;
          Ksm[rl * KSTR + cl] = f2bf(acc[i][j][r] + kb);
        }
    }
  } else {
    int vt = (wm * 2 + (wn - 2)) * 64 + lane;   // 0..255
    int trk = vt >> 3;
    int c0 = (vt & 7) * 32;
    int trkg = trk0 + trk;
    ushort* dst = qsm + trk * QSTR + c0;
    if (trkg < N) {
      const uint4* src = (const uint4*)(qbuf + (size_t)trkg * DD + c0);
      ((uint4*)dst)[0] = src[0];
      ((uint4*)dst)[1] = src[1];
      ((uint4*)dst)[2] = src[2];
      ((uint4*)dst)[3] = src[3];
    } else {
      uint4 z = {0, 0, 0, 0};
      ((uint4*)dst)[0] = z; ((uint4*)dst)[1] = z;
      ((uint4*)dst)[2] = z; ((uint4*)dst)[3] = z;
    }
  }
  __syncthreads();

  // ---- phase 2: K waves do logits+softmax; V waves do bank shift/copy
  //      (mem_bank rows still L2-hot from the A staging) ----
  if (wn < 2) {
    int vt = (wm * 2 + wn) * 64 + lane;   // 0..255
    int trk = vt >> 3, hh = vt & 7;
    int trkg = trk0 + trk;
    if (trkg < N) {
      float qv[32];
      const bf16x8* qp8 = (const bf16x8*)(qsm + trk * QSTR + hh * 32);
#pragma unroll
      for (int c8 = 0; c8 < 4; c8++) {
        bf16x8 q8 = qp8[c8];
#pragma unroll
        for (int e = 0; e < 8; e++) qv[c8 * 8 + e] = (float)q8[e];
      }
      bool valid = !mval(mask, fmt, (size_t)trkg * 4 + 3);
      float lg[4];
      float mx = -3.0e38f;
#pragma unroll
      for (int l = 0; l < 4; l++) {
        const bf16x8* kp8 = (const bf16x8*)(Ksm + (trk * 4 + l) * KSTR + hh * 32);
        float dot = 0.0f;
#pragma unroll
        for (int c8 = 0; c8 < 4; c8++) {
          bf16x8 k8 = kp8[c8];
#pragma unroll
          for (int e = 0; e < 8; e++) dot += qv[c8 * 8 + e] * (float)k8[e];
        }
        dot *= 0.17677669529663687f;
        if (valid && mval(mask, fmt, (size_t)trkg * 4 + l)) dot = -1.0e9f;
        lg[l] = dot;
        mx = fmaxf(mx, dot);
      }
      float sum = 0.0f;
#pragma unroll
      for (int l = 0; l < 4; l++) { lg[l] = expf(lg[l] - mx); sum += lg[l]; }
      float inv = 1.0f / sum;
#pragma unroll
      for (int l = 0; l < 4; l++) attn_s[trk * 32 + hh * 4 + l] = lg[l] * inv;
    }
  } else {
    int vt = (wm * 2 + (wn - 2)) * 64 + lane;   // 0..255
    int rl = vt >> 1;                           // 0..127 (dst bank row within tile)
    int chunk = (vt & 1) * 128;                 // half-row of 256 floats
    int trk = rl >> 2, l = rl & 3;
    int trkg = trk0 + trk;
    if (trkg < N) {
      bool saved = scores[trkg] > 0.0f;
      if (chunk == 0) {
        bool mv = saved ? (l < 3 ? mval(mask, fmt, (size_t)trkg * 4 + l + 1) : false)
                        : mval(mask, fmt, (size_t)trkg * 4 + l);
        out_mask[(size_t)trkg * 4 + l] = mv ? 1.0f : 0.0f;
      }
      if (!(saved && l == 3)) {    // slot3-of-saved is written by the save gemm later
        int ls = saved ? l + 1 : l;
        const float4* s = (const float4*)(memb + ((size_t)trkg * 4 + ls) * DD + chunk);
        float4* d = (float4*)(out_bank + ((size_t)trkg * 4 + l) * DD + chunk);
#pragma unroll 8
        for (int q = 0; q < 32; q++) d[q] = s[q];
      }
    }
  }
  __syncthreads();

  // ---- phase 3: V waves reduce ctx from fp32 accumulators (sum attn = 1,
  //      so the V bias folds in additively) ----
  if (wn >= 2) {
#pragma unroll
    for (int j = 0; j < 8; j++) {
      int vcol = (wn - 2) * 128 + j * 16 + llo;
      float vb = ipb[512 + vcol];
      int h4 = (vcol >> 5) * 4;
#pragma unroll
      for (int i = 0; i < 4; i++) {
        int t = wm * 16 + i * 4 + lhi;
        int trkg = trk0 + t;
        if (trkg < N) {
          const float* at = attn_s + t * 32 + h4;
          float v = at[0] * acc[i][j][0] + at[1] * acc[i][j][1]
                  + at[2] * acc[i][j][2] + at[3] * acc[i][j][3] + vb;
          ctx_out[(size_t)trkg * DD + vcol] = f2bf(v);
        }
      }
    }
  }
}

__global__ __launch_bounds__(256)
void ln1_k(const float* __restrict__ emb, const ushort* __restrict__ ao,
           const float* __restrict__ g, const float* __restrict__ b,
           ushort* __restrict__ eout, int N) {
  int row = blockIdx.x * 4 + (threadIdx.x >> 6);
  if (row >= N) return;
  int lane = threadIdx.x & 63;
  int c = lane * 4;
  float4 xe = *(const float4*)(emb + (size_t)row * DD + c);
  ushort4 xa = *(const ushort4*)(ao + (size_t)row * DD + c);
  float x0 = xe.x + bf2f(xa.x), x1 = xe.y + bf2f(xa.y);
  float x2 = xe.z + bf2f(xa.z), x3 = xe.w + bf2f(xa.w);
  float s = x0 + x1 + x2 + x3;
  float s2 = x0 * x0 + x1 * x1 + x2 * x2 + x3 * x3;
  for (int off = 1; off < 64; off <<= 1) {
    s += __shfl_xor(s, off);
    s2 += __shfl_xor(s2, off);
  }
  float mu = s * (1.0f / 256.0f);
  float var = s2 * (1.0f / 256.0f) - mu * mu;
  float rs = rsqrtf(var + 1e-5f);
  float4 gv = *(const float4*)(g + c);
  float4 bv = *(const float4*)(b + c);
  ushort4 r;
  r.x = f2bf((x0 - mu) * rs * gv.x + bv.x);
  r.y = f2bf((x1 - mu) * rs * gv.y + bv.y);
  r.z = f2bf((x2 - mu) * rs * gv.z + bv.z);
  r.w = f2bf((x3 - mu) * rs * gv.w + bv.w);
  *(ushort4*)(eout + (size_t)row * DD + c) = r;
}

__global__ __launch_bounds__(256)
void ln2_k(const float* __restrict__ emb, const ushort* __restrict__ e,
           const ushort* __restrict__ f, const float* __restrict__ g,
           const float* __restrict__ b, const void* __restrict__ mask,
           const int* __restrict__ flag, float* __restrict__ out_emb, int N) {
  int row = blockIdx.x * 4 + (threadIdx.x >> 6);
  if (row >= N) return;
  int lane = threadIdx.x & 63;
  int c = lane * 4;
  int fmt = *flag;
  bool valid = !mval(mask, fmt, (size_t)row * 4 + 3);
  ushort4 xe = *(const ushort4*)(e + (size_t)row * DD + c);
  ushort4 xf = *(const ushort4*)(f + (size_t)row * DD + c);
  float x0 = bf2f(xe.x) + bf2f(xf.x), x1 = bf2f(xe.y) + bf2f(xf.y);
  float x2 = bf2f(xe.z) + bf2f(xf.z), x3 = bf2f(xe.w) + bf2f(xf.w);
  float s = x0 + x1 + x2 + x3;
  float s2 = x0 * x0 + x1 * x1 + x2 * x2 + x3 * x3;
  for (int off = 1; off < 64; off <<= 1) {
    s += __shfl_xor(s, off);
    s2 += __shfl_xor(s2, off);
  }
  float mu = s * (1.0f / 256.0f);
  float var = s2 * (1.0f / 256.0f) - mu * mu;
  float rs = rsqrtf(var + 1e-5f);
  float4 gv = *(const float4*)(g + c);
  float4 bv = *(const float4*)(b + c);
  float4 o;
  if (valid) {
    o.x = (x0 - mu) * rs * gv.x + bv.x;
    o.y = (x1 - mu) * rs * gv.y + bv.y;
    o.z = (x2 - mu) * rs * gv.z + bv.z;
    o.w = (x3 - mu) * rs * gv.w + bv.w;
  } else {
    o = *(const float4*)(emb + (size_t)row * DD + c);
  }
  *(float4*)(out_emb + (size_t)row * DD + c) = o;
}

extern "C" void kernel_launch(void* const* d_in, const int* in_sizes, int n_in,
                              void* d_out, int out_size, void* d_ws, size_t ws_size,
                              hipStream_t stream) {
  const float* emb = (const float*)d_in[0];
  const float* scores = (const float*)d_in[1];
  const float* memb = (const float*)d_in[2];
  const void* mask = d_in[3];
  const float* svw = (const float*)d_in[4];
  const float* svb = (const float*)d_in[5];
  const float* ipw = (const float*)d_in[6];
  const float* ipb = (const float*)d_in[7];
  const float* opw = (const float*)d_in[8];
  const float* opb = (const float*)d_in[9];
  const float* f1w = (const float*)d_in[10];
  const float* f1b = (const float*)d_in[11];
  const float* f2w = (const float*)d_in[12];
  const float* f2b = (const float*)d_in[13];
  const float* g1 = (const float*)d_in[14];
  const float* b1 = (const float*)d_in[15];
  const float* g2 = (const float*)d_in[16];
  const float* b2 = (const float*)d_in[17];

  const int N = in_sizes[1];

  float* out = (float*)d_out;
  float* out_emb = out;
  float* out_bank = out + (size_t)N * DD;
  float* out_mask = out + (size_t)N * DD + (size_t)N * LL * DD;

  char* ws = (char*)d_ws;
  ushort* W = (ushort*)ws;                       // 458752 bf16 weights
  int* flag = (int*)(ws + 917504);
  size_t o = 1048576;
  ushort* bufQ = (ushort*)(ws + o); o += (size_t)N * DD * 2;   // q, later h
  ushort* bufC = (ushort*)(ws + o); o += (size_t)N * DD * 2;   // ctx, later fc2-out
  ushort* bufE = (ushort*)(ws + o); o += (size_t)N * DD * 2;   // e (post-LN1)
  ushort* bufA = (ushort*)(ws + o); o += (size_t)N * DD * 2;   // attn_out

  cast_w_k<<<(458752 + 255) / 256, 256, 0, stream>>>(ipw, opw, f1w, f2w, svw, W);
  detect_mask_k<<<1, 64, 0, stream>>>((const uint8_t*)mask, flag);

  const int mtN = (N + BM - 1) / BM;
  const int mtKV = (N * LL + 127) / 128;
  const dim3 blk(256);
  const size_t SM_KV = (size_t)128 * KSTR * 2 + (size_t)32 * QSTR * 2 + 32 * 32 * 4; // 55808

  // q = emb @ Wq^T + bq
  gemm_k<0, 0><<<dim3(2, mtN), blk, 0, stream>>>(emb, W, ipb, bufQ, N,
      nullptr, nullptr, 0);
  // fused: K/V proj + logits + softmax + ctx + bank shift/copy + new mask
  kv_attn_k<<<dim3(mtKV), dim3(512), SM_KV, stream>>>(memb, W + 65536, ipb, bufQ,
      bufC, mask, flag, scores, out_bank, out_mask, N);
  // attn_out = ctx @ Wo^T + bo
  gemm_k<1, 0><<<dim3(2, mtN), blk, 0, stream>>>(bufC, W + 196608, opb, bufA, N,
      nullptr, nullptr, 0);
  // e = LN1(emb + attn_out)
  ln1_k<<<(N + 3) / 4, 256, 0, stream>>>(emb, bufA, g1, b1, bufE, N);
  // h = relu(e @ fc1^T + b1)
  gemm_k<1, 0><<<dim3(2, mtN), blk, 0, stream>>>(bufE, W + 262144, f1b, bufQ, N,
      nullptr, nullptr, 1);
  // f = h @ fc2^T + b2
  gemm_k<1, 0><<<dim3(2, mtN), blk, 0, stream>>>(bufQ, W + 327680, f2b, bufC, N,
      nullptr, nullptr, 0);
  // new_emb = valid ? LN2(e + f) : emb   (fp32 -> d_out)
  ln2_k<<<(N + 3) / 4, 256, 0, stream>>>(emb, bufE, bufC, g2, b2, mask, flag, out_emb, N);
  // save_embed -> bank slot 3 for saved rows
  gemm_k<0, 3><<<dim3(2, mtN), blk, 0, stream>>>(out_emb, W + 393216, svb, nullptr, N,
      scores, out_bank, 0);
}